// Round 3
// baseline (2999.168 us; speedup 1.0000x reference)
//
#include <hip/hip_runtime.h>
#include <hip/hip_bf16.h>
#include <math.h>

// Problem constants
#define BB    2
#define NN    1024
#define PAST  1024
#define KVL   2048            // PAST + NN
#define DIM   2048
#define HEADS 16
#define DH    128
#define INNER 2048            // HEADS*DH
#define NQKV  6144            // 3*INNER
#define TOK   2048            // BB*NN
#define LN_EPS 1e-5f

// ---------------------------------------------------------------------------
// K1: LayerNorm over DIM=2048. One block per token, 256 threads, 8 elems each.
// ---------------------------------------------------------------------------
__global__ __launch_bounds__(256) void ln_kernel(
    const float* __restrict__ x, const float* __restrict__ g,
    const float* __restrict__ b, float* __restrict__ xn)
{
    const int t   = blockIdx.x;
    const int tid = threadIdx.x;
    const size_t base = (size_t)t * DIM;

    // 8 f32 = two float4 per thread
    float4 p0 = reinterpret_cast<const float4*>(x + base)[tid * 2 + 0];
    float4 p1 = reinterpret_cast<const float4*>(x + base)[tid * 2 + 1];
    float v[8] = {p0.x, p0.y, p0.z, p0.w, p1.x, p1.y, p1.z, p1.w};

    float s1 = 0.f, s2 = 0.f;
    #pragma unroll
    for (int i = 0; i < 8; i++) { s1 += v[i]; s2 += v[i] * v[i]; }

    // wave (64) reduce, then cross-wave via LDS
    #pragma unroll
    for (int off = 32; off; off >>= 1) {
        s1 += __shfl_xor(s1, off);
        s2 += __shfl_xor(s2, off);
    }
    __shared__ float red1[4], red2[4];
    if ((tid & 63) == 0) { red1[tid >> 6] = s1; red2[tid >> 6] = s2; }
    __syncthreads();
    float S1 = red1[0] + red1[1] + red1[2] + red1[3];
    float S2 = red2[0] + red2[1] + red2[2] + red2[3];
    const float inv = 1.0f / (float)DIM;
    float mu  = S1 * inv;
    float var = S2 * inv - mu * mu;
    float rstd = rsqrtf(var + LN_EPS);

    const int d0 = tid * 8;
    float o[8];
    #pragma unroll
    for (int i = 0; i < 8; i++)
        o[i] = (v[i] - mu) * rstd * g[d0 + i] + b[d0 + i];

    float4* outp = reinterpret_cast<float4*>(xn + base);
    outp[tid * 2 + 0] = make_float4(o[0], o[1], o[2], o[3]);
    outp[tid * 2 + 1] = make_float4(o[4], o[5], o[6], o[7]);
}

// ---------------------------------------------------------------------------
// K2/K5: tiled GEMM  C[M,Nn] = A[M,K] @ Bw[K,Nn]   (all f32)
// BM=BN=64, BK=16, 256 threads, 4x4 micro-tile per thread.
// ---------------------------------------------------------------------------
__global__ __launch_bounds__(256) void gemm_kernel(
    const float* __restrict__ A, const float* __restrict__ Bw,
    float* __restrict__ C, int M, int Nn, int K)
{
    __shared__ __align__(16) float As[16][68];  // A^T tile (k-major), +4 pad
    __shared__ __align__(16) float Bs[16][64];

    const int tid = threadIdx.x;
    const int tx = tid & 15, ty = tid >> 4;
    const int m0 = blockIdx.y * 64;
    const int n0 = blockIdx.x * 64;

    float acc[4][4];
    #pragma unroll
    for (int i = 0; i < 4; i++)
        #pragma unroll
        for (int j = 0; j < 4; j++) acc[i][j] = 0.f;

    // loader indices
    const int a_row = tid >> 2, a_c4 = (tid & 3) * 4;       // A: 64 rows x 16 k
    const int b_row = tid >> 4, b_c4 = (tid & 15) * 4;      // B: 16 k x 64 n

    for (int k0 = 0; k0 < K; k0 += 16) {
        float4 av = *reinterpret_cast<const float4*>(
            &A[(size_t)(m0 + a_row) * K + k0 + a_c4]);
        As[a_c4 + 0][a_row] = av.x;
        As[a_c4 + 1][a_row] = av.y;
        As[a_c4 + 2][a_row] = av.z;
        As[a_c4 + 3][a_row] = av.w;

        float4 bv = *reinterpret_cast<const float4*>(
            &Bw[(size_t)(k0 + b_row) * Nn + n0 + b_c4]);
        *reinterpret_cast<float4*>(&Bs[b_row][b_c4]) = bv;

        __syncthreads();
        #pragma unroll
        for (int kk = 0; kk < 16; kk++) {
            float4 a4 = *reinterpret_cast<const float4*>(&As[kk][ty * 4]);
            float4 b4 = *reinterpret_cast<const float4*>(&Bs[kk][tx * 4]);
            float a[4] = {a4.x, a4.y, a4.z, a4.w};
            float b[4] = {b4.x, b4.y, b4.z, b4.w};
            #pragma unroll
            for (int i = 0; i < 4; i++)
                #pragma unroll
                for (int j = 0; j < 4; j++)
                    acc[i][j] = fmaf(a[i], b[j], acc[i][j]);
        }
        __syncthreads();
    }

    #pragma unroll
    for (int i = 0; i < 4; i++) {
        size_t row = (size_t)(m0 + ty * 4 + i);
        #pragma unroll
        for (int j = 0; j < 4; j++)
            C[row * Nn + n0 + tx * 4 + j] = acc[i][j];
    }
}

// ---------------------------------------------------------------------------
// K3: RoPE + KV cache assembly (all f32).
//  - out_k[b,h,pos,:] = rope(pos<PAST ? past_k : new k from qkv, pos)
//  - out_v[b,h,pos,:] = pos<PAST ? past_v : new v from qkv
//  - q in qkv roped IN PLACE at pos = PAST+n
// 64 lanes per position; lane i handles interleaved pair (2i, 2i+1).
// ---------------------------------------------------------------------------
__global__ __launch_bounds__(256) void rope_kernel(
    const float* __restrict__ past_k, const float* __restrict__ past_v,
    float* __restrict__ qkv, float* __restrict__ out_k, float* __restrict__ out_v)
{
    const int tid  = threadIdx.x;
    const int pid  = blockIdx.x * 4 + (tid >> 6);   // 0 .. B*H*KVL-1
    const int lane = tid & 63;

    const int b   = pid / (HEADS * KVL);
    const int rem = pid - b * (HEADS * KVL);
    const int h   = rem / KVL;
    const int pos = rem - h * KVL;

    // inv_freq = 10000^(-2*lane/128) = 2^(-lane/64 * log2(10000))
    const float invf = exp2f((float)lane * (-13.287712379549449f / 64.0f));
    float sn, cs;
    sincosf((float)pos * invf, &sn, &cs);

    const size_t obase = ((size_t)(b * HEADS + h) * KVL + pos) * DH + 2 * lane;

    // ----- K -----
    float k0, k1;
    if (pos < PAST) {
        const size_t pbase = ((size_t)(b * HEADS + h) * PAST + pos) * DH + 2 * lane;
        k0 = past_k[pbase];
        k1 = past_k[pbase + 1];
    } else {
        const int t = b * NN + (pos - PAST);
        const float* qp = qkv + (size_t)t * NQKV + INNER + h * DH + 2 * lane;
        k0 = qp[0]; k1 = qp[1];
    }
    out_k[obase]     = k0 * cs - k1 * sn;
    out_k[obase + 1] = k1 * cs + k0 * sn;

    // ----- V -----
    if (pos < PAST) {
        const size_t pbase = ((size_t)(b * HEADS + h) * PAST + pos) * DH + 2 * lane;
        out_v[obase]     = past_v[pbase];
        out_v[obase + 1] = past_v[pbase + 1];
    } else {
        const int t = b * NN + (pos - PAST);
        const float* vp = qkv + (size_t)t * NQKV + 2 * INNER + h * DH + 2 * lane;
        out_v[obase]     = vp[0];
        out_v[obase + 1] = vp[1];
    }

    // ----- Q (in place) -----
    if (pos >= PAST) {
        const int t = b * NN + (pos - PAST);
        float* qq = qkv + (size_t)t * NQKV + h * DH + 2 * lane;
        float q0 = qq[0], q1 = qq[1];
        qq[0] = q0 * cs - q1 * sn;
        qq[1] = q1 * cs + q0 * sn;
    }
}

// ---------------------------------------------------------------------------
// K4: attention with online softmax. Block = (qt,h,b): 16 queries, 256 thr.
// KV chunks of 32 rows staged in LDS; f32 accumulate; causal mask analytic.
// ---------------------------------------------------------------------------
__global__ __launch_bounds__(256) void attn_kernel(
    const float* __restrict__ qkv, const float* __restrict__ Kc,
    const float* __restrict__ Vc, float* __restrict__ Ao)
{
    const int qt = blockIdx.x, h = blockIdx.y, b = blockIdx.z;
    const int tid = threadIdx.x;

    __shared__ float Qs[16][129];
    __shared__ float Os[16][128];
    __shared__ float Ks[32][129];
    __shared__ float Vs[32][129];
    __shared__ float Ss[16][33];
    __shared__ float mrow[16], lrow[16], arow[16];

    // load Q tile (post-rope, f32 from qkv) + init O
    #pragma unroll
    for (int e = 0; e < 8; e++) {
        int idx = tid + e * 256;
        int r = idx >> 7, d = idx & 127;
        int t = b * NN + qt * 16 + r;
        Qs[r][d] = qkv[(size_t)t * NQKV + h * DH + d];
        Os[r][d] = 0.f;
    }
    if (tid < 16) { mrow[tid] = -INFINITY; lrow[tid] = 0.f; }
    __syncthreads();

    const size_t kvbase = (size_t)(b * HEADS + h) * KVL * DH;
    const int q0 = PAST + qt * 16;
    const int nch = (q0 + 16 + 31) >> 5;
    const float scale = 0.08838834764831845f;  // 128^-0.5

    for (int c = 0; c < nch; c++) {
        const int j0 = c * 32;
        #pragma unroll
        for (int e = 0; e < 16; e++) {
            int idx = tid + e * 256;
            int jr = idx >> 7, d = idx & 127;
            size_t src = kvbase + (size_t)(j0 + jr) * DH + d;
            Ks[jr][d] = Kc[src];
            Vs[jr][d] = Vc[src];
        }
        __syncthreads();

        // scores: thread -> (r = tid>>4, j in {jj, jj+16})
        {
            int r = tid >> 4, jj = tid & 15;
            float a0 = 0.f, a1 = 0.f;
            #pragma unroll 4
            for (int d = 0; d < 128; d++) {
                float qv = Qs[r][d];
                a0 = fmaf(qv, Ks[jj][d], a0);
                a1 = fmaf(qv, Ks[jj + 16][d], a1);
            }
            int qpos = q0 + r;
            Ss[r][jj]      = (j0 + jj      <= qpos) ? a0 * scale : -INFINITY;
            Ss[r][jj + 16] = (j0 + jj + 16 <= qpos) ? a1 * scale : -INFINITY;
        }
        __syncthreads();

        if (tid < 16) {
            int r = tid;
            float m = mrow[r], mc = -INFINITY;
            #pragma unroll
            for (int j = 0; j < 32; j++) mc = fmaxf(mc, Ss[r][j]);
            float nm = fmaxf(m, mc);
            float alpha = __expf(m - nm);
            float ls = 0.f;
            #pragma unroll
            for (int j = 0; j < 32; j++) {
                float p = __expf(Ss[r][j] - nm);
                Ss[r][j] = p;
                ls += p;
            }
            lrow[r] = lrow[r] * alpha + ls;
            mrow[r] = nm;
            arow[r] = alpha;
        }
        __syncthreads();

        #pragma unroll
        for (int e = 0; e < 8; e++) {
            int idx = tid + e * 256;
            int r = idx >> 7, d = idx & 127;
            float o = Os[r][d] * arow[r];
            #pragma unroll 8
            for (int j = 0; j < 32; j++) o = fmaf(Ss[r][j], Vs[j][d], o);
            Os[r][d] = o;
        }
        __syncthreads();
    }

    #pragma unroll
    for (int e = 0; e < 8; e++) {
        int idx = tid + e * 256;
        int r = idx >> 7, d = idx & 127;
        int t = b * NN + qt * 16 + r;
        Ao[(size_t)t * INNER + h * DH + d] = Os[r][d] / lrow[r];
    }
}

// ---------------------------------------------------------------------------
extern "C" void kernel_launch(void* const* d_in, const int* in_sizes, int n_in,
                              void* d_out, int out_size, void* d_ws, size_t ws_size,
                              hipStream_t stream)
{
    const float* x      = (const float*)d_in[0];
    const float* past_k = (const float*)d_in[1];
    const float* past_v = (const float*)d_in[2];
    // d_in[3] = mask (unused; computed analytically)
    const float* w_qkv  = (const float*)d_in[4];
    const float* w_out  = (const float*)d_in[5];
    const float* ln_g   = (const float*)d_in[6];
    const float* ln_b   = (const float*)d_in[7];

    float* out   = (float*)d_out;                      // [B,N,DIM]
    float* out_k = out   + (size_t)BB * NN * DIM;      // [B,H,KVL,DH]
    float* out_v = out_k + (size_t)BB * HEADS * KVL * DH;

    float* xn   = (float*)d_ws;                        // [TOK, DIM]
    float* qkv  = xn  + (size_t)TOK * DIM;             // [TOK, NQKV]
    float* attn = qkv + (size_t)TOK * NQKV;            // [TOK, INNER]

    ln_kernel<<<TOK, 256, 0, stream>>>(x, ln_g, ln_b, xn);

    gemm_kernel<<<dim3(NQKV / 64, TOK / 64), 256, 0, stream>>>(
        xn, w_qkv, qkv, TOK, NQKV, DIM);

    rope_kernel<<<(BB * HEADS * KVL) / 4, 256, 0, stream>>>(
        past_k, past_v, qkv, out_k, out_v);

    attn_kernel<<<dim3(NN / 16, HEADS, BB), 256, 0, stream>>>(
        qkv, out_k, out_v, attn);

    gemm_kernel<<<dim3(DIM / 64, TOK / 64), 256, 0, stream>>>(
        attn, w_out, out, TOK, DIM, INNER);
}

// Round 4
// 1242.096 us; speedup vs baseline: 2.4146x; 2.4146x over previous
//
#include <hip/hip_runtime.h>
#include <hip/hip_bf16.h>
#include <math.h>

// Problem constants
#define BB    2
#define NN    1024
#define PAST  1024
#define KVL   2048            // PAST + NN
#define DIM   2048
#define HEADS 16
#define DH    128
#define INNER 2048            // HEADS*DH
#define NQKV  6144            // 3*INNER
#define TOK   2048            // BB*NN
#define LN_EPS 1e-5f

typedef __attribute__((ext_vector_type(8))) short   short8;   // 8 bf16 (4 VGPR)
typedef __attribute__((ext_vector_type(4))) float   f32x4;
typedef __attribute__((ext_vector_type(8))) unsigned short us8;
typedef __attribute__((ext_vector_type(4))) unsigned short us4;

__device__ __forceinline__ unsigned short f2bfb(float f) {
    union { __hip_bfloat16 h; unsigned short u; } cv;
    cv.h = __float2bfloat16(f);           // RNE
    return cv.u;
}
__device__ __forceinline__ short8 pack8(float4 a, float4 b) {
    union { us8 u; short8 s; } r;
    r.u[0] = f2bfb(a.x); r.u[1] = f2bfb(a.y); r.u[2] = f2bfb(a.z); r.u[3] = f2bfb(a.w);
    r.u[4] = f2bfb(b.x); r.u[5] = f2bfb(b.y); r.u[6] = f2bfb(b.z); r.u[7] = f2bfb(b.w);
    return r.s;
}

// ---------------------------------------------------------------------------
// K1: LayerNorm over DIM=2048. One block per token, 256 threads, 8 elems each.
// ---------------------------------------------------------------------------
__global__ __launch_bounds__(256) void ln_kernel(
    const float* __restrict__ x, const float* __restrict__ g,
    const float* __restrict__ b, float* __restrict__ xn)
{
    const int t   = blockIdx.x;
    const int tid = threadIdx.x;
    const size_t base = (size_t)t * DIM;

    float4 p0 = reinterpret_cast<const float4*>(x + base)[tid * 2 + 0];
    float4 p1 = reinterpret_cast<const float4*>(x + base)[tid * 2 + 1];
    float v[8] = {p0.x, p0.y, p0.z, p0.w, p1.x, p1.y, p1.z, p1.w};

    float s1 = 0.f, s2 = 0.f;
    #pragma unroll
    for (int i = 0; i < 8; i++) { s1 += v[i]; s2 += v[i] * v[i]; }

    #pragma unroll
    for (int off = 32; off; off >>= 1) {
        s1 += __shfl_xor(s1, off);
        s2 += __shfl_xor(s2, off);
    }
    __shared__ float red1[4], red2[4];
    if ((tid & 63) == 0) { red1[tid >> 6] = s1; red2[tid >> 6] = s2; }
    __syncthreads();
    float S1 = red1[0] + red1[1] + red1[2] + red1[3];
    float S2 = red2[0] + red2[1] + red2[2] + red2[3];
    const float inv = 1.0f / (float)DIM;
    float mu  = S1 * inv;
    float var = S2 * inv - mu * mu;
    float rstd = rsqrtf(var + LN_EPS);

    const int d0 = tid * 8;
    float o[8];
    #pragma unroll
    for (int i = 0; i < 8; i++)
        o[i] = (v[i] - mu) * rstd * g[d0 + i] + b[d0 + i];

    float4* outp = reinterpret_cast<float4*>(xn + base);
    outp[tid * 2 + 0] = make_float4(o[0], o[1], o[2], o[3]);
    outp[tid * 2 + 1] = make_float4(o[4], o[5], o[6], o[7]);
}

// ---------------------------------------------------------------------------
// K2/K5: tiled GEMM  C[M,Nn] = A[M,K] @ Bw[K,Nn]   (all f32)
// ---------------------------------------------------------------------------
__global__ __launch_bounds__(256) void gemm_kernel(
    const float* __restrict__ A, const float* __restrict__ Bw,
    float* __restrict__ C, int M, int Nn, int K)
{
    __shared__ __align__(16) float As[16][68];
    __shared__ __align__(16) float Bs[16][64];

    const int tid = threadIdx.x;
    const int tx = tid & 15, ty = tid >> 4;
    const int m0 = blockIdx.y * 64;
    const int n0 = blockIdx.x * 64;

    float acc[4][4];
    #pragma unroll
    for (int i = 0; i < 4; i++)
        #pragma unroll
        for (int j = 0; j < 4; j++) acc[i][j] = 0.f;

    const int a_row = tid >> 2, a_c4 = (tid & 3) * 4;
    const int b_row = tid >> 4, b_c4 = (tid & 15) * 4;

    for (int k0 = 0; k0 < K; k0 += 16) {
        float4 av = *reinterpret_cast<const float4*>(
            &A[(size_t)(m0 + a_row) * K + k0 + a_c4]);
        As[a_c4 + 0][a_row] = av.x;
        As[a_c4 + 1][a_row] = av.y;
        As[a_c4 + 2][a_row] = av.z;
        As[a_c4 + 3][a_row] = av.w;

        float4 bv = *reinterpret_cast<const float4*>(
            &Bw[(size_t)(k0 + b_row) * Nn + n0 + b_c4]);
        *reinterpret_cast<float4*>(&Bs[b_row][b_c4]) = bv;

        __syncthreads();
        #pragma unroll
        for (int kk = 0; kk < 16; kk++) {
            float4 a4 = *reinterpret_cast<const float4*>(&As[kk][ty * 4]);
            float4 b4 = *reinterpret_cast<const float4*>(&Bs[kk][tx * 4]);
            float a[4] = {a4.x, a4.y, a4.z, a4.w};
            float b[4] = {b4.x, b4.y, b4.z, b4.w};
            #pragma unroll
            for (int i = 0; i < 4; i++)
                #pragma unroll
                for (int j = 0; j < 4; j++)
                    acc[i][j] = fmaf(a[i], b[j], acc[i][j]);
        }
        __syncthreads();
    }

    #pragma unroll
    for (int i = 0; i < 4; i++) {
        size_t row = (size_t)(m0 + ty * 4 + i);
        #pragma unroll
        for (int j = 0; j < 4; j++)
            C[row * Nn + n0 + tx * 4 + j] = acc[i][j];
    }
}

// ---------------------------------------------------------------------------
// K3: RoPE + KV cache assembly (all f32). Unchanged from round 3.
// ---------------------------------------------------------------------------
__global__ __launch_bounds__(256) void rope_kernel(
    const float* __restrict__ past_k, const float* __restrict__ past_v,
    float* __restrict__ qkv, float* __restrict__ out_k, float* __restrict__ out_v)
{
    const int tid  = threadIdx.x;
    const int pid  = blockIdx.x * 4 + (tid >> 6);
    const int lane = tid & 63;

    const int b   = pid / (HEADS * KVL);
    const int rem = pid - b * (HEADS * KVL);
    const int h   = rem / KVL;
    const int pos = rem - h * KVL;

    const float invf = exp2f((float)lane * (-13.287712379549449f / 64.0f));
    float sn, cs;
    sincosf((float)pos * invf, &sn, &cs);

    const size_t obase = ((size_t)(b * HEADS + h) * KVL + pos) * DH + 2 * lane;

    float k0, k1;
    if (pos < PAST) {
        const size_t pbase = ((size_t)(b * HEADS + h) * PAST + pos) * DH + 2 * lane;
        k0 = past_k[pbase];
        k1 = past_k[pbase + 1];
    } else {
        const int t = b * NN + (pos - PAST);
        const float* qp = qkv + (size_t)t * NQKV + INNER + h * DH + 2 * lane;
        k0 = qp[0]; k1 = qp[1];
    }
    out_k[obase]     = k0 * cs - k1 * sn;
    out_k[obase + 1] = k1 * cs + k0 * sn;

    if (pos < PAST) {
        const size_t pbase = ((size_t)(b * HEADS + h) * PAST + pos) * DH + 2 * lane;
        out_v[obase]     = past_v[pbase];
        out_v[obase + 1] = past_v[pbase + 1];
    } else {
        const int t = b * NN + (pos - PAST);
        const float* vp = qkv + (size_t)t * NQKV + 2 * INNER + h * DH + 2 * lane;
        out_v[obase]     = vp[0];
        out_v[obase + 1] = vp[1];
    }

    if (pos >= PAST) {
        const int t = b * NN + (pos - PAST);
        float* qq = qkv + (size_t)t * NQKV + h * DH + 2 * lane;
        float q0 = qq[0], q1 = qq[1];
        qq[0] = q0 * cs - q1 * sn;
        qq[1] = q1 * cs + q0 * sn;
    }
}

// ---------------------------------------------------------------------------
// K3b: V transpose to bf16: Vtg[bh][d][kv] <- bf16(out_v[bh][kv][d])
// 64x64 LDS tile; coalesced read f32, coalesced write bf16.
// ---------------------------------------------------------------------------
__global__ __launch_bounds__(256) void vtrans_kernel(
    const float* __restrict__ Vc, unsigned short* __restrict__ Vtg)
{
    const int jb = blockIdx.x;           // key tile  (KVL/64)
    const int db = blockIdx.y;           // dh tile   (DH/64)
    const int bh = blockIdx.z;           // b*HEADS+h
    const int tid = threadIdx.x;

    __shared__ unsigned short T[64][68];  // [key][dh], 136B rows

    const float* src = Vc + ((size_t)bh * KVL + jb * 64) * DH + db * 64;
    #pragma unroll
    for (int e = 0; e < 4; e++) {
        int idx = tid + e * 256;          // 1024 float4 tasks
        int jr  = idx >> 4;               // 16 float4 per row
        int c4  = (idx & 15) * 4;
        float4 v = *reinterpret_cast<const float4*>(src + (size_t)jr * DH + c4);
        us4 w;
        w[0] = f2bfb(v.x); w[1] = f2bfb(v.y); w[2] = f2bfb(v.z); w[3] = f2bfb(v.w);
        *reinterpret_cast<us4*>(&T[jr][c4]) = w;
    }
    __syncthreads();

    unsigned short* dst = Vtg + ((size_t)bh * DH + db * 64) * KVL + jb * 64;
    #pragma unroll
    for (int e = 0; e < 4; e++) {
        int idx = tid + e * 256;
        int d   = idx >> 4;               // dh row within tile
        int k4  = (idx & 15) * 4;
        us4 w;
        w[0] = T[k4 + 0][d];
        w[1] = T[k4 + 1][d];
        w[2] = T[k4 + 2][d];
        w[3] = T[k4 + 3][d];
        *reinterpret_cast<us4*>(dst + (size_t)d * KVL + k4) = w;
    }
}

// ---------------------------------------------------------------------------
// K4: MFMA flash attention. Block = 64 queries x (h, b); 4 waves; KV chunk 64.
// Layouts (HW-verified, 16x16x32 bf16):
//   C/D: col = lane&15, row = (lane>>4)*4 + reg
//   A:   A[m = lane&15][k = (lane>>4)*8 + j]
//   B:   B[k = (lane>>4)*8 + j][n = lane&15]
// ---------------------------------------------------------------------------
__global__ __launch_bounds__(256) void attn_mfma_kernel(
    const float* __restrict__ qkv,            // [TOK][NQKV], q roped in place
    const float* __restrict__ Kc,             // [b,h,KVL,DH] f32 (roped)
    const unsigned short* __restrict__ Vtg,   // [bh][DH][KVL] bf16
    float* __restrict__ Ao)                   // [TOK][INNER] f32
{
    const int qt   = blockIdx.x;              // 0..15
    const int h    = blockIdx.y;
    const int b    = blockIdx.z;
    const int tid  = threadIdx.x;
    const int wave = tid >> 6;
    const int lane = tid & 63;
    const int quad = lane >> 4;
    const int l16  = lane & 15;

    __shared__ unsigned short Ks[64][136];    // [key][dh], 272B rows (2-way free)
    __shared__ unsigned short Vt[128][72];    // [dh][key], 144B rows
    __shared__ unsigned short Pb[64][72];     // [query][key] per-wave rows

    // --- Q A-fragments: registers, loaded once ---
    short8 qf[4];
    {
        const int qrow = qt * 64 + wave * 16 + l16;
        const float* qp = qkv + (size_t)(b * NN + qrow) * NQKV + h * DH;
        #pragma unroll
        for (int ks = 0; ks < 4; ks++) {
            const float* p = qp + ks * 32 + quad * 8;
            float4 x0 = *reinterpret_cast<const float4*>(p);
            float4 x1 = *reinterpret_cast<const float4*>(p + 4);
            qf[ks] = pack8(x0, x1);
        }
    }

    f32x4 Oacc[8];
    #pragma unroll
    for (int t = 0; t < 8; t++)
        #pragma unroll
        for (int r = 0; r < 4; r++) Oacc[t][r] = 0.f;
    float mrow[4] = {-INFINITY, -INFINITY, -INFINITY, -INFINITY};
    float lrow[4] = {0.f, 0.f, 0.f, 0.f};

    const size_t kbase = (size_t)(b * HEADS + h) * KVL * DH;
    const unsigned short* vtb = Vtg + (size_t)(b * HEADS + h) * DH * KVL;
    const float scale = 0.08838834764831845f;  // 128^-0.5
    const int qg = PAST + qt * 64 + wave * 16 + quad * 4;  // global pos of reg r=0
    const int nch = 17 + qt;

    for (int c = 0; c < nch; c++) {
        const int j0 = c * 64;

        // ---- stage K (f32->bf16) and Vt (bf16 copy) ----
        #pragma unroll
        for (int e = 0; e < 4; e++) {
            int idx = tid + e * 256;              // 1024 groups of 8
            int jr  = idx >> 4;                   // 16 groups per key row
            int c8  = (idx & 15) * 8;
            const float* src = Kc + kbase + (size_t)(j0 + jr) * DH + c8;
            float4 x0 = *reinterpret_cast<const float4*>(src);
            float4 x1 = *reinterpret_cast<const float4*>(src + 4);
            union { us8 u; short8 s; } w;
            w.s = pack8(x0, x1);
            *reinterpret_cast<us8*>(&Ks[jr][c8]) = w.u;
        }
        #pragma unroll
        for (int e = 0; e < 4; e++) {
            int idx = tid + e * 256;
            int d   = idx >> 3;                   // 8 groups per dh row
            int c8  = (idx & 7) * 8;
            *reinterpret_cast<uint4*>(&Vt[d][c8]) =
                *reinterpret_cast<const uint4*>(vtb + (size_t)d * KVL + j0 + c8);
        }
        __syncthreads();

        // ---- S = Q K^T (16 MFMAs) ----
        f32x4 S[4];
        #pragma unroll
        for (int t = 0; t < 4; t++)
            #pragma unroll
            for (int r = 0; r < 4; r++) S[t][r] = 0.f;
        #pragma unroll
        for (int ks = 0; ks < 4; ks++) {
            #pragma unroll
            for (int t = 0; t < 4; t++) {
                short8 kb = *reinterpret_cast<const short8*>(
                    &Ks[t * 16 + l16][ks * 32 + quad * 8]);
                S[t] = __builtin_amdgcn_mfma_f32_16x16x32_bf16(qf[ks], kb, S[t], 0, 0, 0);
            }
        }

        // ---- scale + causal mask (only diagonal chunk ever masks) ----
        #pragma unroll
        for (int t = 0; t < 4; t++) {
            int kg = j0 + t * 16 + l16;
            #pragma unroll
            for (int r = 0; r < 4; r++) {
                float s = S[t][r] * scale;
                S[t][r] = (kg <= qg + r) ? s : -INFINITY;
            }
        }

        // ---- online softmax (in-register, shfl within 16-lane groups) ----
        float alpha[4];
        #pragma unroll
        for (int r = 0; r < 4; r++) {
            float mx = fmaxf(fmaxf(S[0][r], S[1][r]), fmaxf(S[2][r], S[3][r]));
            mx = fmaxf(mx, __shfl_xor(mx, 1));
            mx = fmaxf(mx, __shfl_xor(mx, 2));
            mx = fmaxf(mx, __shfl_xor(mx, 4));
            mx = fmaxf(mx, __shfl_xor(mx, 8));
            float nm = fmaxf(mrow[r], mx);
            alpha[r] = __expf(mrow[r] - nm);
            mrow[r] = nm;
            float rs = 0.f;
            #pragma unroll
            for (int t = 0; t < 4; t++) {
                float p = __expf(S[t][r] - nm);
                S[t][r] = p;
                rs += p;
            }
            rs += __shfl_xor(rs, 1);
            rs += __shfl_xor(rs, 2);
            rs += __shfl_xor(rs, 4);
            rs += __shfl_xor(rs, 8);
            lrow[r] = lrow[r] * alpha[r] + rs;
        }

        // ---- rescale O ----
        #pragma unroll
        for (int t = 0; t < 8; t++)
            #pragma unroll
            for (int r = 0; r < 4; r++) Oacc[t][r] *= alpha[r];

        // ---- P (C-layout) -> LDS -> A-layout ----
        #pragma unroll
        for (int t = 0; t < 4; t++)
            #pragma unroll
            for (int r = 0; r < 4; r++)
                Pb[wave * 16 + quad * 4 + r][t * 16 + l16] = f2bfb(S[t][r]);
        __syncthreads();

        // ---- O += P V (16 MFMAs) ----
        #pragma unroll
        for (int kh = 0; kh < 2; kh++) {
            short8 pa = *reinterpret_cast<const short8*>(
                &Pb[wave * 16 + l16][kh * 32 + quad * 8]);
            #pragma unroll
            for (int t2 = 0; t2 < 8; t2++) {
                short8 vb = *reinterpret_cast<const short8*>(
                    &Vt[t2 * 16 + l16][kh * 32 + quad * 8]);
                Oacc[t2] = __builtin_amdgcn_mfma_f32_16x16x32_bf16(pa, vb, Oacc[t2], 0, 0, 0);
            }
        }
        __syncthreads();
    }

    // ---- epilogue: O / l -> Ao ----
    float invl[4];
    #pragma unroll
    for (int r = 0; r < 4; r++) invl[r] = 1.f / lrow[r];
    const int row0 = b * NN + qt * 64 + wave * 16 + quad * 4;
    #pragma unroll
    for (int r = 0; r < 4; r++) {
        float* dst = Ao + (size_t)(row0 + r) * INNER + h * DH + l16;
        #pragma unroll
        for (int t2 = 0; t2 < 8; t2++)
            dst[t2 * 16] = Oacc[t2][r] * invl[r];
    }
}

// ---------------------------------------------------------------------------
extern "C" void kernel_launch(void* const* d_in, const int* in_sizes, int n_in,
                              void* d_out, int out_size, void* d_ws, size_t ws_size,
                              hipStream_t stream)
{
    const float* x      = (const float*)d_in[0];
    const float* past_k = (const float*)d_in[1];
    const float* past_v = (const float*)d_in[2];
    // d_in[3] = mask (unused; computed analytically)
    const float* w_qkv  = (const float*)d_in[4];
    const float* w_out  = (const float*)d_in[5];
    const float* ln_g   = (const float*)d_in[6];
    const float* ln_b   = (const float*)d_in[7];

    float* out   = (float*)d_out;                      // [B,N,DIM]
    float* out_k = out   + (size_t)BB * NN * DIM;      // [B,H,KVL,DH]
    float* out_v = out_k + (size_t)BB * HEADS * KVL * DH;

    // ws: xn [TOK][DIM] f32 (reused as attn-out) | qkv [TOK][NQKV] f32 | Vtg bf16
    float* xn   = (float*)d_ws;
    float* qkv  = xn + (size_t)TOK * DIM;
    unsigned short* Vtg = (unsigned short*)(qkv + (size_t)TOK * NQKV);
    float* attn = xn;   // alias: xn dead after GEMM1

    ln_kernel<<<TOK, 256, 0, stream>>>(x, ln_g, ln_b, xn);

    gemm_kernel<<<dim3(NQKV / 64, TOK / 64), 256, 0, stream>>>(
        xn, w_qkv, qkv, TOK, NQKV, DIM);

    rope_kernel<<<(BB * HEADS * KVL) / 4, 256, 0, stream>>>(
        past_k, past_v, qkv, out_k, out_v);

    vtrans_kernel<<<dim3(KVL / 64, DH / 64, BB * HEADS), 256, 0, stream>>>(
        out_v, Vtg);

    attn_mfma_kernel<<<dim3(NN / 64, HEADS, BB), 256, 0, stream>>>(
        qkv, out_k, Vtg, attn);

    gemm_kernel<<<dim3(DIM / 64, TOK / 64), 256, 0, stream>>>(
        attn, w_out, out, TOK, DIM, INNER);
}

// Round 5
// 479.546 us; speedup vs baseline: 6.2542x; 2.5902x over previous
//
#include <hip/hip_runtime.h>
#include <hip/hip_bf16.h>
#include <math.h>

// Problem constants
#define BB    2
#define NN    1024
#define PAST  1024
#define KVL   2048            // PAST + NN
#define DIM   2048
#define HEADS 16
#define DH    128
#define INNER 2048            // HEADS*DH
#define NQKV  6144            // 3*INNER
#define TOK   2048            // BB*NN
#define LN_EPS 1e-5f

typedef __attribute__((ext_vector_type(8))) short   short8;   // 8 bf16 (4 VGPR)
typedef __attribute__((ext_vector_type(4))) float   f32x4;
typedef __attribute__((ext_vector_type(8))) unsigned short us8;
typedef __attribute__((ext_vector_type(4))) unsigned short us4;
typedef unsigned short us;

__device__ __forceinline__ float bfbits2f(us u) {
    return __uint_as_float(((unsigned int)u) << 16);
}
__device__ __forceinline__ us f2bfb(float f) {
    union { __hip_bfloat16 h; us u; } cv;
    cv.h = __float2bfloat16(f);           // RNE
    return cv.u;
}
__device__ __forceinline__ us8 pack8u(float4 a, float4 b) {
    us8 r;
    r[0] = f2bfb(a.x); r[1] = f2bfb(a.y); r[2] = f2bfb(a.z); r[3] = f2bfb(a.w);
    r[4] = f2bfb(b.x); r[5] = f2bfb(b.y); r[6] = f2bfb(b.z); r[7] = f2bfb(b.w);
    return r;
}

// ---------------------------------------------------------------------------
// K0: transpose + cast: dst[C][R] (bf16) <- src[R][C] (f32). 64x64 tiles.
// ---------------------------------------------------------------------------
__global__ __launch_bounds__(256) void transp_kernel(
    const float* __restrict__ src, us* __restrict__ dst, int R, int C)
{
    const int c0 = blockIdx.x * 64;
    const int r0 = blockIdx.y * 64;
    const int tid = threadIdx.x;

    __shared__ us T[64][68];

    #pragma unroll
    for (int e = 0; e < 4; e++) {
        int idx = tid + e * 256;
        int jr  = idx >> 4;               // row within tile
        int c4  = (idx & 15) * 4;
        float4 v = *reinterpret_cast<const float4*>(
            src + (size_t)(r0 + jr) * C + c0 + c4);
        us4 w;
        w[0] = f2bfb(v.x); w[1] = f2bfb(v.y); w[2] = f2bfb(v.z); w[3] = f2bfb(v.w);
        *reinterpret_cast<us4*>(&T[jr][c4]) = w;
    }
    __syncthreads();

    #pragma unroll
    for (int e = 0; e < 4; e++) {
        int idx = tid + e * 256;
        int d   = idx >> 4;               // col within tile (dst row)
        int k4  = (idx & 15) * 4;
        us4 w;
        w[0] = T[k4 + 0][d];
        w[1] = T[k4 + 1][d];
        w[2] = T[k4 + 2][d];
        w[3] = T[k4 + 3][d];
        *reinterpret_cast<us4*>(dst + (size_t)(c0 + d) * R + r0 + k4) = w;
    }
}

// ---------------------------------------------------------------------------
// K1: LayerNorm over DIM=2048 -> bf16. One block per token.
// ---------------------------------------------------------------------------
__global__ __launch_bounds__(256) void ln_kernel(
    const float* __restrict__ x, const float* __restrict__ g,
    const float* __restrict__ b, us* __restrict__ xn)
{
    const int t   = blockIdx.x;
    const int tid = threadIdx.x;
    const size_t base = (size_t)t * DIM;

    float4 p0 = reinterpret_cast<const float4*>(x + base)[tid * 2 + 0];
    float4 p1 = reinterpret_cast<const float4*>(x + base)[tid * 2 + 1];
    float v[8] = {p0.x, p0.y, p0.z, p0.w, p1.x, p1.y, p1.z, p1.w};

    float s1 = 0.f, s2 = 0.f;
    #pragma unroll
    for (int i = 0; i < 8; i++) { s1 += v[i]; s2 += v[i] * v[i]; }

    #pragma unroll
    for (int off = 32; off; off >>= 1) {
        s1 += __shfl_xor(s1, off);
        s2 += __shfl_xor(s2, off);
    }
    __shared__ float red1[4], red2[4];
    if ((tid & 63) == 0) { red1[tid >> 6] = s1; red2[tid >> 6] = s2; }
    __syncthreads();
    float S1 = red1[0] + red1[1] + red1[2] + red1[3];
    float S2 = red2[0] + red2[1] + red2[2] + red2[3];
    const float inv = 1.0f / (float)DIM;
    float mu  = S1 * inv;
    float var = S2 * inv - mu * mu;
    float rstd = rsqrtf(var + LN_EPS);

    const int d0 = tid * 8;
    float4 oa, ob;
    oa.x = (v[0] - mu) * rstd * g[d0 + 0] + b[d0 + 0];
    oa.y = (v[1] - mu) * rstd * g[d0 + 1] + b[d0 + 1];
    oa.z = (v[2] - mu) * rstd * g[d0 + 2] + b[d0 + 2];
    oa.w = (v[3] - mu) * rstd * g[d0 + 3] + b[d0 + 3];
    ob.x = (v[4] - mu) * rstd * g[d0 + 4] + b[d0 + 4];
    ob.y = (v[5] - mu) * rstd * g[d0 + 5] + b[d0 + 5];
    ob.z = (v[6] - mu) * rstd * g[d0 + 6] + b[d0 + 6];
    ob.w = (v[7] - mu) * rstd * g[d0 + 7] + b[d0 + 7];

    *reinterpret_cast<us8*>(xn + base + d0) = pack8u(oa, ob);
}

// ---------------------------------------------------------------------------
// K2/K5: MFMA GEMM (B^T layout):  C[M][N] = A[M][K] @ Bt[N][K]^T  (bf16 in)
// 128x128 tile, BK=32, 256 thr (2x2 waves, 64x64 per wave, 4x4 MFMA grid).
// LDS rows stride 40 shorts (80B) -> 16B aligned, low-conflict.
// ---------------------------------------------------------------------------
template<bool OUT_BF16>
__global__ __launch_bounds__(256) void gemm_bt_kernel(
    const us* __restrict__ A, const us* __restrict__ Bt,
    void* __restrict__ Cout, int M, int N, int K)
{
    __shared__ us As[128][40];
    __shared__ us Bs[128][40];

    const int tid  = threadIdx.x;
    const int wave = tid >> 6, lane = tid & 63;
    const int quad = lane >> 4, l16 = lane & 15;
    const int wm = wave & 1, wn = wave >> 1;
    const int m0 = blockIdx.y * 128, n0 = blockIdx.x * 128;

    f32x4 acc[4][4];
    #pragma unroll
    for (int i = 0; i < 4; i++)
        #pragma unroll
        for (int j = 0; j < 4; j++)
            #pragma unroll
            for (int r = 0; r < 4; r++) acc[i][j][r] = 0.f;

    const int s_row = tid >> 2;          // 0..63
    const int s_c8  = (tid & 3) * 8;     // 0,8,16,24

    const us* pa0 = A  + (size_t)(m0 + s_row)      * K + s_c8;
    const us* pa1 = A  + (size_t)(m0 + 64 + s_row) * K + s_c8;
    const us* pb0 = Bt + (size_t)(n0 + s_row)      * K + s_c8;
    const us* pb1 = Bt + (size_t)(n0 + 64 + s_row) * K + s_c8;

    for (int k0 = 0; k0 < K; k0 += 32) {
        us8 a0 = *reinterpret_cast<const us8*>(pa0 + k0);
        us8 a1 = *reinterpret_cast<const us8*>(pa1 + k0);
        us8 b0 = *reinterpret_cast<const us8*>(pb0 + k0);
        us8 b1 = *reinterpret_cast<const us8*>(pb1 + k0);

        __syncthreads();   // previous tile fully consumed
        *reinterpret_cast<us8*>(&As[s_row][s_c8])      = a0;
        *reinterpret_cast<us8*>(&As[64 + s_row][s_c8]) = a1;
        *reinterpret_cast<us8*>(&Bs[s_row][s_c8])      = b0;
        *reinterpret_cast<us8*>(&Bs[64 + s_row][s_c8]) = b1;
        __syncthreads();

        short8 af[4], bf[4];
        #pragma unroll
        for (int mi = 0; mi < 4; mi++)
            af[mi] = *reinterpret_cast<const short8*>(
                &As[wm * 64 + mi * 16 + l16][quad * 8]);
        #pragma unroll
        for (int ni = 0; ni < 4; ni++)
            bf[ni] = *reinterpret_cast<const short8*>(
                &Bs[wn * 64 + ni * 16 + l16][quad * 8]);

        #pragma unroll
        for (int mi = 0; mi < 4; mi++)
            #pragma unroll
            for (int ni = 0; ni < 4; ni++)
                acc[mi][ni] = __builtin_amdgcn_mfma_f32_16x16x32_bf16(
                    af[mi], bf[ni], acc[mi][ni], 0, 0, 0);
    }

    // epilogue: C/D layout col=l16, row=quad*4+r
    #pragma unroll
    for (int mi = 0; mi < 4; mi++) {
        #pragma unroll
        for (int r = 0; r < 4; r++) {
            size_t row = (size_t)(m0 + wm * 64 + mi * 16 + quad * 4 + r);
            #pragma unroll
            for (int ni = 0; ni < 4; ni++) {
                size_t col = n0 + wn * 64 + ni * 16 + l16;
                if (OUT_BF16)
                    ((us*)Cout)[row * N + col] = f2bfb(acc[mi][ni][r]);
                else
                    ((float*)Cout)[row * N + col] = acc[mi][ni][r];
            }
        }
    }
}

// ---------------------------------------------------------------------------
// K3: RoPE + KV cache assembly. qkv is bf16 now; outputs f32.
// ---------------------------------------------------------------------------
__global__ __launch_bounds__(256) void rope_kernel(
    const float* __restrict__ past_k, const float* __restrict__ past_v,
    us* __restrict__ qkv, float* __restrict__ out_k, float* __restrict__ out_v)
{
    const int tid  = threadIdx.x;
    const int pid  = blockIdx.x * 4 + (tid >> 6);
    const int lane = tid & 63;

    const int b   = pid / (HEADS * KVL);
    const int rem = pid - b * (HEADS * KVL);
    const int h   = rem / KVL;
    const int pos = rem - h * KVL;

    const float invf = exp2f((float)lane * (-13.287712379549449f / 64.0f));
    float sn, cs;
    sincosf((float)pos * invf, &sn, &cs);

    const size_t obase = ((size_t)(b * HEADS + h) * KVL + pos) * DH + 2 * lane;

    float k0, k1;
    if (pos < PAST) {
        const size_t pbase = ((size_t)(b * HEADS + h) * PAST + pos) * DH + 2 * lane;
        k0 = past_k[pbase];
        k1 = past_k[pbase + 1];
    } else {
        const int t = b * NN + (pos - PAST);
        const us* qp = qkv + (size_t)t * NQKV + INNER + h * DH + 2 * lane;
        k0 = bfbits2f(qp[0]); k1 = bfbits2f(qp[1]);
    }
    out_k[obase]     = k0 * cs - k1 * sn;
    out_k[obase + 1] = k1 * cs + k0 * sn;

    if (pos < PAST) {
        const size_t pbase = ((size_t)(b * HEADS + h) * PAST + pos) * DH + 2 * lane;
        out_v[obase]     = past_v[pbase];
        out_v[obase + 1] = past_v[pbase + 1];
    } else {
        const int t = b * NN + (pos - PAST);
        const us* vp = qkv + (size_t)t * NQKV + 2 * INNER + h * DH + 2 * lane;
        out_v[obase]     = bfbits2f(vp[0]);
        out_v[obase + 1] = bfbits2f(vp[1]);
    }

    if (pos >= PAST) {
        const int t = b * NN + (pos - PAST);
        us* qq = qkv + (size_t)t * NQKV + h * DH + 2 * lane;
        float q0 = bfbits2f(qq[0]), q1 = bfbits2f(qq[1]);
        qq[0] = f2bfb(q0 * cs - q1 * sn);
        qq[1] = f2bfb(q1 * cs + q0 * sn);
    }
}

// ---------------------------------------------------------------------------
// K3b: V transpose to bf16: Vtg[bh][d][kv] <- bf16(out_v[bh][kv][d])
// ---------------------------------------------------------------------------
__global__ __launch_bounds__(256) void vtrans_kernel(
    const float* __restrict__ Vc, us* __restrict__ Vtg)
{
    const int jb = blockIdx.x;
    const int db = blockIdx.y;
    const int bh = blockIdx.z;
    const int tid = threadIdx.x;

    __shared__ us T[64][68];

    const float* src = Vc + ((size_t)bh * KVL + jb * 64) * DH + db * 64;
    #pragma unroll
    for (int e = 0; e < 4; e++) {
        int idx = tid + e * 256;
        int jr  = idx >> 4;
        int c4  = (idx & 15) * 4;
        float4 v = *reinterpret_cast<const float4*>(src + (size_t)jr * DH + c4);
        us4 w;
        w[0] = f2bfb(v.x); w[1] = f2bfb(v.y); w[2] = f2bfb(v.z); w[3] = f2bfb(v.w);
        *reinterpret_cast<us4*>(&T[jr][c4]) = w;
    }
    __syncthreads();

    us* dst = Vtg + ((size_t)bh * DH + db * 64) * KVL + jb * 64;
    #pragma unroll
    for (int e = 0; e < 4; e++) {
        int idx = tid + e * 256;
        int d   = idx >> 4;
        int k4  = (idx & 15) * 4;
        us4 w;
        w[0] = T[k4 + 0][d];
        w[1] = T[k4 + 1][d];
        w[2] = T[k4 + 2][d];
        w[3] = T[k4 + 3][d];
        *reinterpret_cast<us4*>(dst + (size_t)d * KVL + k4) = w;
    }
}

// ---------------------------------------------------------------------------
// K4: MFMA flash attention. Block = 64 queries x (h, b); 4 waves; KV chunk 64.
// ---------------------------------------------------------------------------
__global__ __launch_bounds__(256) void attn_mfma_kernel(
    const us* __restrict__ qkv,               // [TOK][NQKV] bf16, q roped
    const float* __restrict__ Kc,             // [b,h,KVL,DH] f32 (roped)
    const us* __restrict__ Vtg,               // [bh][DH][KVL] bf16
    us* __restrict__ Ao)                      // [TOK][INNER] bf16
{
    const int qt   = blockIdx.x;
    const int h    = blockIdx.y;
    const int b    = blockIdx.z;
    const int tid  = threadIdx.x;
    const int wave = tid >> 6;
    const int lane = tid & 63;
    const int quad = lane >> 4;
    const int l16  = lane & 15;

    __shared__ us Ks[64][136];
    __shared__ us Vt[128][72];
    __shared__ us Pb[64][72];

    // Q A-fragments: direct bf16 loads
    short8 qf[4];
    {
        const int qrow = qt * 64 + wave * 16 + l16;
        const us* qp = qkv + (size_t)(b * NN + qrow) * NQKV + h * DH;
        #pragma unroll
        for (int ks = 0; ks < 4; ks++)
            qf[ks] = *reinterpret_cast<const short8*>(qp + ks * 32 + quad * 8);
    }

    f32x4 Oacc[8];
    #pragma unroll
    for (int t = 0; t < 8; t++)
        #pragma unroll
        for (int r = 0; r < 4; r++) Oacc[t][r] = 0.f;
    float mrow[4] = {-INFINITY, -INFINITY, -INFINITY, -INFINITY};
    float lrow[4] = {0.f, 0.f, 0.f, 0.f};

    const size_t kbase = (size_t)(b * HEADS + h) * KVL * DH;
    const us* vtb = Vtg + (size_t)(b * HEADS + h) * DH * KVL;
    const float scale = 0.08838834764831845f;
    const int qg = PAST + qt * 64 + wave * 16 + quad * 4;
    const int nch = 17 + qt;

    for (int c = 0; c < nch; c++) {
        const int j0 = c * 64;

        #pragma unroll
        for (int e = 0; e < 4; e++) {
            int idx = tid + e * 256;
            int jr  = idx >> 4;
            int c8  = (idx & 15) * 8;
            const float* src = Kc + kbase + (size_t)(j0 + jr) * DH + c8;
            float4 x0 = *reinterpret_cast<const float4*>(src);
            float4 x1 = *reinterpret_cast<const float4*>(src + 4);
            *reinterpret_cast<us8*>(&Ks[jr][c8]) = pack8u(x0, x1);
        }
        #pragma unroll
        for (int e = 0; e < 4; e++) {
            int idx = tid + e * 256;
            int d   = idx >> 3;
            int c8  = (idx & 7) * 8;
            *reinterpret_cast<uint4*>(&Vt[d][c8]) =
                *reinterpret_cast<const uint4*>(vtb + (size_t)d * KVL + j0 + c8);
        }
        __syncthreads();

        f32x4 S[4];
        #pragma unroll
        for (int t = 0; t < 4; t++)
            #pragma unroll
            for (int r = 0; r < 4; r++) S[t][r] = 0.f;
        #pragma unroll
        for (int ks = 0; ks < 4; ks++) {
            #pragma unroll
            for (int t = 0; t < 4; t++) {
                short8 kb = *reinterpret_cast<const short8*>(
                    &Ks[t * 16 + l16][ks * 32 + quad * 8]);
                S[t] = __builtin_amdgcn_mfma_f32_16x16x32_bf16(qf[ks], kb, S[t], 0, 0, 0);
            }
        }

        #pragma unroll
        for (int t = 0; t < 4; t++) {
            int kg = j0 + t * 16 + l16;
            #pragma unroll
            for (int r = 0; r < 4; r++) {
                float s = S[t][r] * scale;
                S[t][r] = (kg <= qg + r) ? s : -INFINITY;
            }
        }

        float alpha[4];
        #pragma unroll
        for (int r = 0; r < 4; r++) {
            float mx = fmaxf(fmaxf(S[0][r], S[1][r]), fmaxf(S[2][r], S[3][r]));
            mx = fmaxf(mx, __shfl_xor(mx, 1));
            mx = fmaxf(mx, __shfl_xor(mx, 2));
            mx = fmaxf(mx, __shfl_xor(mx, 4));
            mx = fmaxf(mx, __shfl_xor(mx, 8));
            float nm = fmaxf(mrow[r], mx);
            alpha[r] = __expf(mrow[r] - nm);
            mrow[r] = nm;
            float rs = 0.f;
            #pragma unroll
            for (int t = 0; t < 4; t++) {
                float p = __expf(S[t][r] - nm);
                S[t][r] = p;
                rs += p;
            }
            rs += __shfl_xor(rs, 1);
            rs += __shfl_xor(rs, 2);
            rs += __shfl_xor(rs, 4);
            rs += __shfl_xor(rs, 8);
            lrow[r] = lrow[r] * alpha[r] + rs;
        }

        #pragma unroll
        for (int t = 0; t < 8; t++)
            #pragma unroll
            for (int r = 0; r < 4; r++) Oacc[t][r] *= alpha[r];

        #pragma unroll
        for (int t = 0; t < 4; t++)
            #pragma unroll
            for (int r = 0; r < 4; r++)
                Pb[wave * 16 + quad * 4 + r][t * 16 + l16] = f2bfb(S[t][r]);
        __syncthreads();

        #pragma unroll
        for (int kh = 0; kh < 2; kh++) {
            short8 pa = *reinterpret_cast<const short8*>(
                &Pb[wave * 16 + l16][kh * 32 + quad * 8]);
            #pragma unroll
            for (int t2 = 0; t2 < 8; t2++) {
                short8 vb = *reinterpret_cast<const short8*>(
                    &Vt[t2 * 16 + l16][kh * 32 + quad * 8]);
                Oacc[t2] = __builtin_amdgcn_mfma_f32_16x16x32_bf16(pa, vb, Oacc[t2], 0, 0, 0);
            }
        }
        __syncthreads();
    }

    float invl[4];
    #pragma unroll
    for (int r = 0; r < 4; r++) invl[r] = 1.f / lrow[r];
    const int row0 = b * NN + qt * 64 + wave * 16 + quad * 4;
    #pragma unroll
    for (int r = 0; r < 4; r++) {
        us* dst = Ao + (size_t)(row0 + r) * INNER + h * DH + l16;
        #pragma unroll
        for (int t2 = 0; t2 < 8; t2++)
            dst[t2 * 16] = f2bfb(Oacc[t2][r] * invl[r]);
    }
}

// ---------------------------------------------------------------------------
extern "C" void kernel_launch(void* const* d_in, const int* in_sizes, int n_in,
                              void* d_out, int out_size, void* d_ws, size_t ws_size,
                              hipStream_t stream)
{
    const float* x      = (const float*)d_in[0];
    const float* past_k = (const float*)d_in[1];
    const float* past_v = (const float*)d_in[2];
    // d_in[3] = mask (unused; computed analytically)
    const float* w_qkv  = (const float*)d_in[4];
    const float* w_out  = (const float*)d_in[5];
    const float* ln_g   = (const float*)d_in[6];
    const float* ln_b   = (const float*)d_in[7];

    float* out   = (float*)d_out;                      // [B,N,DIM]
    float* out_k = out   + (size_t)BB * NN * DIM;      // [B,H,KVL,DH]
    float* out_v = out_k + (size_t)BB * HEADS * KVL * DH;

    // ws (bf16 buffers), 80 MB total:
    us* xn   = (us*)d_ws;                              // [TOK][DIM]     8 MB
    us* qkv  = xn  + (size_t)TOK * DIM;                // [TOK][NQKV]   24 MB
    us* Wqt  = qkv + (size_t)TOK * NQKV;               // [NQKV][DIM]   24 MB
    us* Wot  = Wqt + (size_t)NQKV * DIM;               // [DIM][INNER]   8 MB
    us* Vtg  = Wot + (size_t)DIM * INNER;              // [bh][DH][KVL] 16 MB
    us* attn = xn;   // alias: xn dead after qkv GEMM  // [TOK][INNER]   8 MB

    transp_kernel<<<dim3(NQKV / 64, DIM / 64), 256, 0, stream>>>(
        w_qkv, Wqt, DIM, NQKV);
    transp_kernel<<<dim3(DIM / 64, INNER / 64), 256, 0, stream>>>(
        w_out, Wot, INNER, DIM);

    ln_kernel<<<TOK, 256, 0, stream>>>(x, ln_g, ln_b, xn);

    gemm_bt_kernel<true><<<dim3(NQKV / 128, TOK / 128), 256, 0, stream>>>(
        xn, Wqt, (void*)qkv, TOK, NQKV, DIM);

    rope_kernel<<<(BB * HEADS * KVL) / 4, 256, 0, stream>>>(
        past_k, past_v, qkv, out_k, out_v);

    vtrans_kernel<<<dim3(KVL / 64, DH / 64, BB * HEADS), 256, 0, stream>>>(
        out_v, Vtg);

    attn_mfma_kernel<<<dim3(NN / 64, HEADS, BB), 256, 0, stream>>>(
        qkv, out_k, Vtg, attn);

    gemm_bt_kernel<false><<<dim3(DIM / 128, TOK / 128), 256, 0, stream>>>(
        attn, Wot, (void*)out, TOK, DIM, INNER);
}